// Round 1
// baseline (5911.304 us; speedup 1.0000x reference)
//
#include <hip/hip_runtime.h>
#include <stdint.h>

// ---------------------------------------------------------------------------
// Critic: encoder (5 small dense+relu) -> 255-step LSTM (U=256, D_in=256)
//         -> 1-unit relu head.  B=512.
//
// Round-1 design:
//  k1 encoder  : fp32, 32 blocks x 256 thr, batch tile 16 -> state[512,256] (ws)
//  k2 prep     : Wk/Wrk [256,1024] fp32 -> bf16, transposed AND gate-interleaved
//                n'' = 64*(u>>4) + 16*gate + (u&15); bl reordered likewise.
//  k3 lstm     : 32 blocks x 1024 thr (16 waves), batch tile 16 (MFMA min M).
//                Per step: z = x@Wk + h@Wrk via mfma_f32_16x16x32_bf16,
//                4 N-tiles per wave == the 4 gates of its 16 units, so each
//                lane holds i,f,g,o for (4 rows x 1 unit) in acc[0..3][reg];
//                c stays in registers, gates in fp32, h round-tripped via LDS
//                (bf16) for the next step's A-fragments. Head fused at end.
// ---------------------------------------------------------------------------

#define BTOT 512
#define TSTEPS 128
#define DIN 256
#define NU 256

typedef __attribute__((ext_vector_type(8))) short short8;   // 8 x bf16
typedef __attribute__((ext_vector_type(4))) float f32x4;

__device__ __forceinline__ unsigned short f2bf(float f) {
    union { float f; unsigned int u; } v; v.f = f;
    unsigned int r = v.u + 0x7FFFu + ((v.u >> 16) & 1u);   // RNE
    return (unsigned short)(r >> 16);
}

__device__ __forceinline__ float fexp2(float x) {
#if __has_builtin(__builtin_amdgcn_exp2f)
    return __builtin_amdgcn_exp2f(x);
#else
    return exp2f(x);
#endif
}
__device__ __forceinline__ float frcp(float x) {
#if __has_builtin(__builtin_amdgcn_rcpf)
    return __builtin_amdgcn_rcpf(x);
#else
    return 1.0f / x;
#endif
}
__device__ __forceinline__ float sigm(float x) {
    return frcp(1.0f + fexp2(-1.44269504f * x));
}
__device__ __forceinline__ float tanh_(float x) {
    // tanh(x) = 1 - 2/(exp(2x)+1); saturates gracefully at +-inf
    return 1.0f - 2.0f * frcp(1.0f + fexp2(2.88539008f * x));
}

// ---------------------------------------------------------------------------
// Encoder: state = relu(concat(ms,rs,re,im) @ Wc + bc)
// ---------------------------------------------------------------------------
__global__ __launch_bounds__(256)
void encoder_kernel(const float* __restrict__ motion, const float* __restrict__ robot,
                    const float* __restrict__ osr, const float* __restrict__ osi,
                    const float* __restrict__ ore, const float* __restrict__ oie,
                    const float* __restrict__ Wm, const float* __restrict__ bm,
                    const float* __restrict__ Wr, const float* __restrict__ br,
                    const float* __restrict__ Wre, const float* __restrict__ bre,
                    const float* __restrict__ Wim, const float* __restrict__ bim,
                    const float* __restrict__ Wc, const float* __restrict__ bc,
                    float* __restrict__ state)
{
    __shared__ float catb[16 * 768];
    const int t = threadIdx.x;
    const int m0 = blockIdx.x * 16;

    // Phase A: build concat [16][768] = [ms 256 | rs 256 | re 128 | im 128]
    for (int row = 0; row < 16; ++row) {
        const int b = m0 + row;
        {   // j3 = 0 : ms (u = t)
            float s = bm[t];
            for (int k = 0; k < 64; ++k) s += motion[b * 64 + k] * Wm[k * 256 + t];
            catb[row * 768 + t] = fmaxf(s, 0.0f);
        }
        {   // j3 = 1 : rs (u = t)
            float s = br[t];
            for (int k = 0; k < 128; ++k) s += robot[b * 128 + k] * Wr[k * 256 + t];
            catb[row * 768 + 256 + t] = fmaxf(s, 0.0f);
        }
        {   // j3 = 2 : re (t<128) / im (t>=128)  -- wave-uniform split
            if (t < 128) {
                const int u = t;
                float s = bre[u];
                for (int k = 0; k < 128; ++k) {
                    const float rk = (k < 64) ? osr[b * 64 + k] : ore[b * 64 + (k - 64)];
                    s += rk * Wre[k * 128 + u];
                }
                catb[row * 768 + 512 + u] = fmaxf(s, 0.0f);
            } else {
                const int u = t - 128;
                float s = bim[u];
                for (int k = 0; k < 128; ++k) {
                    const float ik = (k < 64) ? osi[b * 64 + k] : oie[b * 64 + (k - 64)];
                    s += ik * Wim[k * 128 + u];
                }
                catb[row * 768 + 640 + u] = fmaxf(s, 0.0f);
            }
        }
    }
    __syncthreads();

    // Phase B: state = relu(cat @ Wc + bc); 4 rows per pass to reuse Wc loads
    for (int r0 = 0; r0 < 16; r0 += 4) {
        float a0 = bc[t], a1 = bc[t], a2 = bc[t], a3 = bc[t];
        for (int j = 0; j < 768; ++j) {
            const float wv = Wc[j * 256 + t];
            a0 += catb[(r0 + 0) * 768 + j] * wv;
            a1 += catb[(r0 + 1) * 768 + j] * wv;
            a2 += catb[(r0 + 2) * 768 + j] * wv;
            a3 += catb[(r0 + 3) * 768 + j] * wv;
        }
        state[(m0 + r0 + 0) * NU + t] = fmaxf(a0, 0.0f);
        state[(m0 + r0 + 1) * NU + t] = fmaxf(a1, 0.0f);
        state[(m0 + r0 + 2) * NU + t] = fmaxf(a2, 0.0f);
        state[(m0 + r0 + 3) * NU + t] = fmaxf(a3, 0.0f);
    }
}

// ---------------------------------------------------------------------------
// Prep: WkT/WrkT[n''][k] bf16 with gate-interleaved n''; blr reordered.
//   n'' -> (u,g):  u = ((n''>>6)<<4) | (n''&15),  g = (n''>>4)&3,
//   original col = g*256 + u.
// ---------------------------------------------------------------------------
__global__ __launch_bounds__(256)
void prep_kernel(const float* __restrict__ Wk, const float* __restrict__ Wrk,
                 const float* __restrict__ bl,
                 unsigned short* __restrict__ WkT, unsigned short* __restrict__ WrkT,
                 float* __restrict__ blr)
{
    const int blk = blockIdx.x;
    const int t = threadIdx.x;
    if (blk < 2048) {
        const int mat = blk >> 10;
        const int np  = blk & 1023;
        const int u = ((np >> 6) << 4) | (np & 15);
        const int g = (np >> 4) & 3;
        const int no = g * 256 + u;
        const float* W = mat ? Wrk : Wk;
        unsigned short* O = mat ? WrkT : WkT;
        O[np * 256 + t] = f2bf(W[t * 1024 + no]);
    } else {
        for (int j = 0; j < 4; ++j) {
            const int np = t + 256 * j;
            const int u = ((np >> 6) << 4) | (np & 15);
            const int g = (np >> 4) & 3;
            blr[np] = bl[g * 256 + u];
        }
    }
}

// ---------------------------------------------------------------------------
// LSTM: 32 blocks x 1024 threads. Block = batch tile of 16 rows, 255 steps.
// ---------------------------------------------------------------------------
__global__ __launch_bounds__(1024, 4)
void lstm_kernel(const float* __restrict__ hist, const float* __restrict__ act,
                 const float* __restrict__ state,
                 const unsigned short* __restrict__ WkT,
                 const unsigned short* __restrict__ WrkT,
                 const float* __restrict__ blr,
                 const float* __restrict__ Wo, const float* __restrict__ bo_p,
                 float* __restrict__ out)
{
    // 264-short row pitch: even 8-way bank-group spread for ds_read_b128
    __shared__ unsigned short x_bf[16 * 264];
    __shared__ unsigned short h_bf[16 * 264];
    __shared__ float h_fin[16 * 256];

    const int tid  = threadIdx.x;
    const int w    = tid >> 6;          // wave 0..15
    const int lane = tid & 63;
    const int q    = lane >> 4;         // quad 0..3
    const int cid  = lane & 15;
    const int m0   = blockIdx.x * 16;

    // staging mapping: thread -> (row, 4 consecutive k)
    const int srow = tid >> 6;
    const int sk4  = (tid & 63) * 4;

    // init h_bf = bf16(state tile), x_bf = bf16(history[:, 0, :])
    {
        const float4 v = *(const float4*)(state + (m0 + srow) * NU + sk4);
        unsigned short* hp = &h_bf[srow * 264 + sk4];
        hp[0] = f2bf(v.x); hp[1] = f2bf(v.y); hp[2] = f2bf(v.z); hp[3] = f2bf(v.w);
        const float4 u = *(const float4*)(hist + ((m0 + srow) * TSTEPS + 0) * DIN + sk4);
        unsigned short* xq = &x_bf[srow * 264 + sk4];
        xq[0] = f2bf(u.x); xq[1] = f2bf(u.y); xq[2] = f2bf(u.z); xq[3] = f2bf(u.w);
    }

    // per-lane c state: rows q*4+r, unit u = w*16+cid
    const int uu = w * 16 + cid;
    float c0 = state[(m0 + q * 4 + 0) * NU + uu];
    float c1 = state[(m0 + q * 4 + 1) * NU + uu];
    float c2 = state[(m0 + q * 4 + 2) * NU + uu];
    float c3 = state[(m0 + q * 4 + 3) * NU + uu];

    // gate biases for this lane's 4 N-tiles (n'' = 64w + 16g + cid)
    const float bia_i = blr[w * 64 +  0 + cid];
    const float bia_f = blr[w * 64 + 16 + cid];
    const float bia_g = blr[w * 64 + 32 + cid];
    const float bia_o = blr[w * 64 + 48 + cid];

    // invariant base pointers for fragment loads
    const unsigned short* wkp = WkT  + (w * 64 + cid) * 256 + q * 8;
    const unsigned short* wrp = WrkT + (w * 64 + cid) * 256 + q * 8;
    const unsigned short* axp = &x_bf[cid * 264 + q * 8];
    const unsigned short* ahp = &h_bf[cid * 264 + q * 8];

    __syncthreads();

    float h0, h1, h2, h3;
    for (int s = 0; s < 2 * TSTEPS - 1; ++s) {
        f32x4 acc0 = {0.f, 0.f, 0.f, 0.f};
        f32x4 acc1 = {0.f, 0.f, 0.f, 0.f};
        f32x4 acc2 = {0.f, 0.f, 0.f, 0.f};
        f32x4 acc3 = {0.f, 0.f, 0.f, 0.f};

        // z += x @ Wk   (A from x_bf LDS, B from L2-resident WkT)
#pragma unroll
        for (int kk = 0; kk < 8; ++kk) {
            const short8 a = *(const short8*)(axp + kk * 32);
            acc0 = __builtin_amdgcn_mfma_f32_16x16x32_bf16(a, *(const short8*)(wkp + kk * 32          ), acc0, 0, 0, 0);
            acc1 = __builtin_amdgcn_mfma_f32_16x16x32_bf16(a, *(const short8*)(wkp + kk * 32 +  4096  ), acc1, 0, 0, 0);
            acc2 = __builtin_amdgcn_mfma_f32_16x16x32_bf16(a, *(const short8*)(wkp + kk * 32 +  8192  ), acc2, 0, 0, 0);
            acc3 = __builtin_amdgcn_mfma_f32_16x16x32_bf16(a, *(const short8*)(wkp + kk * 32 + 12288  ), acc3, 0, 0, 0);
        }
        // z += h @ Wrk
#pragma unroll
        for (int kk = 0; kk < 8; ++kk) {
            const short8 a = *(const short8*)(ahp + kk * 32);
            acc0 = __builtin_amdgcn_mfma_f32_16x16x32_bf16(a, *(const short8*)(wrp + kk * 32          ), acc0, 0, 0, 0);
            acc1 = __builtin_amdgcn_mfma_f32_16x16x32_bf16(a, *(const short8*)(wrp + kk * 32 +  4096  ), acc1, 0, 0, 0);
            acc2 = __builtin_amdgcn_mfma_f32_16x16x32_bf16(a, *(const short8*)(wrp + kk * 32 +  8192  ), acc2, 0, 0, 0);
            acc3 = __builtin_amdgcn_mfma_f32_16x16x32_bf16(a, *(const short8*)(wrp + kk * 32 + 12288  ), acc3, 0, 0, 0);
        }

        // gates: lane owns (rows q*4+r, unit uu); i,f,g,o = acc0..3[r]
        {
            float zi, zf, zg, zo, si, sf, so, tg;
            zi = acc0[0] + bia_i; zf = acc1[0] + bia_f; zg = acc2[0] + bia_g; zo = acc3[0] + bia_o;
            si = sigm(zi); sf = sigm(zf); so = sigm(zo); tg = tanh_(zg);
            c0 = sf * c0 + si * tg;  h0 = so * tanh_(c0);
            zi = acc0[1] + bia_i; zf = acc1[1] + bia_f; zg = acc2[1] + bia_g; zo = acc3[1] + bia_o;
            si = sigm(zi); sf = sigm(zf); so = sigm(zo); tg = tanh_(zg);
            c1 = sf * c1 + si * tg;  h1 = so * tanh_(c1);
            zi = acc0[2] + bia_i; zf = acc1[2] + bia_f; zg = acc2[2] + bia_g; zo = acc3[2] + bia_o;
            si = sigm(zi); sf = sigm(zf); so = sigm(zo); tg = tanh_(zg);
            c2 = sf * c2 + si * tg;  h2 = so * tanh_(c2);
            zi = acc0[3] + bia_i; zf = acc1[3] + bia_f; zg = acc2[3] + bia_g; zo = acc3[3] + bia_o;
            si = sigm(zi); sf = sigm(zf); so = sigm(zo); tg = tanh_(zg);
            c3 = sf * c3 + si * tg;  h3 = so * tanh_(c3);
        }

        __syncthreads();   // all waves done reading x_bf / h_bf

        h_bf[(q * 4 + 0) * 264 + uu] = f2bf(h0);
        h_bf[(q * 4 + 1) * 264 + uu] = f2bf(h1);
        h_bf[(q * 4 + 2) * 264 + uu] = f2bf(h2);
        h_bf[(q * 4 + 3) * 264 + uu] = f2bf(h3);

        if (s < 2 * TSTEPS - 2) {
            // stage x for step s+1 (history for s+1<127, else action)
            const int sn = s + 1;
            const float* xp = (sn < TSTEPS - 1)
                ? hist + ((m0 + srow) * TSTEPS + sn) * DIN + sk4
                : act  + ((m0 + srow) * TSTEPS + (sn - (TSTEPS - 1))) * DIN + sk4;
            const float4 v = *(const float4*)xp;
            unsigned short* xq = &x_bf[srow * 264 + sk4];
            xq[0] = f2bf(v.x); xq[1] = f2bf(v.y); xq[2] = f2bf(v.z); xq[3] = f2bf(v.w);
        } else {
            // final h in fp32 for the head
            h_fin[(q * 4 + 0) * 256 + uu] = h0;
            h_fin[(q * 4 + 1) * 256 + uu] = h1;
            h_fin[(q * 4 + 2) * 256 + uu] = h2;
            h_fin[(q * 4 + 3) * 256 + uu] = h3;
        }
        __syncthreads();   // writes visible for next step / epilogue
    }

    // head: out[row] = relu(h . Wo + bo); wave w handles row w
    float part = 0.0f;
#pragma unroll
    for (int j = 0; j < 4; ++j) {
        const int u2 = lane + 64 * j;
        part += h_fin[w * 256 + u2] * Wo[u2];
    }
#pragma unroll
    for (int off = 32; off > 0; off >>= 1) part += __shfl_down(part, off, 64);
    if (lane == 0) out[m0 + w] = fmaxf(part + bo_p[0], 0.0f);
}

// ---------------------------------------------------------------------------
extern "C" void kernel_launch(void* const* d_in, const int* in_sizes, int n_in,
                              void* d_out, int out_size, void* d_ws, size_t ws_size,
                              hipStream_t stream)
{
    const float* motion = (const float*)d_in[0];
    const float* robot  = (const float*)d_in[1];
    const float* osr    = (const float*)d_in[2];
    const float* osi    = (const float*)d_in[3];
    const float* hist   = (const float*)d_in[4];
    const float* act    = (const float*)d_in[5];
    const float* ore    = (const float*)d_in[6];
    const float* oie    = (const float*)d_in[7];
    const float* Wm  = (const float*)d_in[8];  const float* bm  = (const float*)d_in[9];
    const float* Wr  = (const float*)d_in[10]; const float* br  = (const float*)d_in[11];
    const float* Wre = (const float*)d_in[12]; const float* bre = (const float*)d_in[13];
    const float* Wim = (const float*)d_in[14]; const float* bim = (const float*)d_in[15];
    const float* Wc  = (const float*)d_in[16]; const float* bc  = (const float*)d_in[17];
    const float* Wk  = (const float*)d_in[18];
    const float* Wrk = (const float*)d_in[19];
    const float* bl  = (const float*)d_in[20];
    const float* Wo  = (const float*)d_in[21]; const float* bo  = (const float*)d_in[22];

    char* ws = (char*)d_ws;
    float*          state = (float*)(ws + 0);                 // 512*256*4  = 524288
    unsigned short* WkT   = (unsigned short*)(ws + 524288);   // 1024*256*2 = 524288
    unsigned short* WrkT  = (unsigned short*)(ws + 1048576);  // 524288
    float*          blr   = (float*)(ws + 1572864);           // 4096
    float*          out   = (float*)d_out;

    encoder_kernel<<<dim3(32), dim3(256), 0, stream>>>(
        motion, robot, osr, osi, ore, oie,
        Wm, bm, Wr, br, Wre, bre, Wim, bim, Wc, bc, state);
    prep_kernel<<<dim3(2049), dim3(256), 0, stream>>>(Wk, Wrk, bl, WkT, WrkT, blr);
    lstm_kernel<<<dim3(32), dim3(1024), 0, stream>>>(
        hist, act, state, WkT, WrkT, blr, Wo, bo, out);
}